// Round 16
// baseline (245.487 us; speedup 1.0000x reference)
//
#include <hip/hip_runtime.h>

#define N_NODES 50000
#define N_EDGES 800000
#define E_TOT   (N_EDGES + N_NODES)
#define IN_DIM  256
#define HID     32
#define HEADS   8
#define D1      256      // HEADS*HID
#define OUT_DIM 16

#define SCAN_NB ((N_NODES + 255) / 256)                     // 196 (1 node per thread)
#define CNT8_NB ((N_EDGES + 2047) / 2048)                   // 391 count blocks (8 edges/thread)
#define G1_NB   ((D1 / 128) * ((N_NODES + 127) / 128))      // 2*391 = 782 gemm1 blocks

typedef __attribute__((ext_vector_type(8))) short bf16x8;
typedef __attribute__((ext_vector_type(4))) float f32x4;
typedef __attribute__((ext_vector_type(4))) _Float16 half4;
typedef __attribute__((ext_vector_type(8))) _Float16 half8;

// ---- f32 <-> bf16 split helpers ----
__device__ __forceinline__ unsigned short f2bf(float f) {
  unsigned u = __float_as_uint(f);
  return (unsigned short)((u + 0x7FFFu + ((u >> 16) & 1u)) >> 16);
}
__device__ __forceinline__ float bf2f(unsigned short b) {
  return __uint_as_float(((unsigned)b) << 16);
}
__device__ __forceinline__ float lrelu(float a) { return (a > 0.f) ? a : 0.2f * a; }

// ---------------- prep: transpose + split W1 only (tiny, 256KB) ----------------
__global__ void prep_w(const float* __restrict__ W, unsigned short* __restrict__ Wth,
                       unsigned short* __restrict__ Wtl) {
  int t = blockIdx.x * blockDim.x + threadIdx.x;
  if (t >= IN_DIM * D1) return;
  int n = t >> 8, k = t & 255;
  float v = W[k * D1 + n];
  unsigned short h = f2bf(v);
  Wth[n * IN_DIM + k] = h;
  Wtl[n * IN_DIM + k] = f2bf(v - bf2f(h));
}

// ---- GEMM1 (fp32 x, in-register split) + attn1 + edge-count fused ----
__global__ __launch_bounds__(256) void gemm1_count(
    const float* __restrict__ x,
    const unsigned short* __restrict__ Bth_g, const unsigned short* __restrict__ Btl_g,
    const float* __restrict__ att_s, const float* __restrict__ att_d,
    _Float16* __restrict__ C, float* __restrict__ as_, float* __restrict__ ad_,
    const int* __restrict__ edst, int* __restrict__ deg4, int* __restrict__ rank) {
  const int bid = blockIdx.x;
  if (bid < CNT8_NB) {
    const int eb = bid * 2048 + threadIdx.x;
    #pragma unroll
    for (int u = 0; u < 8; u++) {
      int e = eb + u * 256;
      if (e < N_EDGES) {
        int d = edst[e];
        rank[e] = atomicAdd(&deg4[(d << 2) + (e & 3)], 1);
      }
    }
    return;
  }
  __shared__ short Ah[128][40], Al[128][40];
  __shared__ short Bh[128][40], Bl[128][40];
  const int gb = bid - CNT8_NB;
  const int bm = (gb >> 1) * 128, bn = (gb & 1) * 128;
  const int tid = threadIdx.x;
  const int wave = tid >> 6, lane = tid & 63;
  const int l15 = lane & 15, l4 = lane >> 4;
  f32x4 acc[8][2] = {};
  const int sr2 = tid >> 1, sc2 = (tid & 1) * 16;
  const bf16x8 zv = {0, 0, 0, 0, 0, 0, 0, 0};
  for (int k0 = 0; k0 < IN_DIM; k0 += 32) {
    int grow = bm + sr2;
    if (grow < N_NODES) {
      const float4* xp = (const float4*)&x[(size_t)grow * IN_DIM + k0 + sc2];
      #pragma unroll
      for (int j = 0; j < 4; j++) {
        float4 v = xp[j];
        ushort4 hh, ll;
        hh.x = f2bf(v.x); ll.x = f2bf(v.x - bf2f(hh.x));
        hh.y = f2bf(v.y); ll.y = f2bf(v.y - bf2f(hh.y));
        hh.z = f2bf(v.z); ll.z = f2bf(v.z - bf2f(hh.z));
        hh.w = f2bf(v.w); ll.w = f2bf(v.w - bf2f(hh.w));
        *(ushort4*)&Ah[sr2][sc2 + j * 4] = hh;
        *(ushort4*)&Al[sr2][sc2 + j * 4] = ll;
      }
    } else {
      *(bf16x8*)&Ah[sr2][sc2] = zv;
      *(bf16x8*)&Ah[sr2][sc2 + 8] = zv;
      *(bf16x8*)&Al[sr2][sc2] = zv;
      *(bf16x8*)&Al[sr2][sc2 + 8] = zv;
    }
    {
      const bf16x8* sH = (const bf16x8*)&Bth_g[(size_t)(bn + sr2) * IN_DIM + k0 + sc2];
      const bf16x8* sL = (const bf16x8*)&Btl_g[(size_t)(bn + sr2) * IN_DIM + k0 + sc2];
      *(bf16x8*)&Bh[sr2][sc2] = sH[0];
      *(bf16x8*)&Bh[sr2][sc2 + 8] = sH[1];
      *(bf16x8*)&Bl[sr2][sc2] = sL[0];
      *(bf16x8*)&Bl[sr2][sc2 + 8] = sL[1];
    }
    __syncthreads();
    bf16x8 bh0 = *(bf16x8*)&Bh[wave * 32 + l15][l4 * 8];
    bf16x8 bl0 = *(bf16x8*)&Bl[wave * 32 + l15][l4 * 8];
    bf16x8 bh1 = *(bf16x8*)&Bh[wave * 32 + 16 + l15][l4 * 8];
    bf16x8 bl1 = *(bf16x8*)&Bl[wave * 32 + 16 + l15][l4 * 8];
    #pragma unroll
    for (int i = 0; i < 8; i++) {
      bf16x8 ah = *(bf16x8*)&Ah[i * 16 + l15][l4 * 8];
      bf16x8 al = *(bf16x8*)&Al[i * 16 + l15][l4 * 8];
      acc[i][0] = __builtin_amdgcn_mfma_f32_16x16x32_bf16(ah, bh0, acc[i][0], 0, 0, 0);
      acc[i][0] = __builtin_amdgcn_mfma_f32_16x16x32_bf16(ah, bl0, acc[i][0], 0, 0, 0);
      acc[i][0] = __builtin_amdgcn_mfma_f32_16x16x32_bf16(al, bh0, acc[i][0], 0, 0, 0);
      acc[i][1] = __builtin_amdgcn_mfma_f32_16x16x32_bf16(ah, bh1, acc[i][1], 0, 0, 0);
      acc[i][1] = __builtin_amdgcn_mfma_f32_16x16x32_bf16(ah, bl1, acc[i][1], 0, 0, 0);
      acc[i][1] = __builtin_amdgcn_mfma_f32_16x16x32_bf16(al, bh1, acc[i][1], 0, 0, 0);
    }
    __syncthreads();
  }
  const int head = (bn >> 5) + wave;
  const float sA0 = att_s[head * HID + l15];
  const float sA1 = att_s[head * HID + 16 + l15];
  const float dA0 = att_d[head * HID + l15];
  const float dA1 = att_d[head * HID + 16 + l15];
  #pragma unroll
  for (int i = 0; i < 8; i++) {
    #pragma unroll
    for (int cf = 0; cf < 2; cf++) {
      const int ccol = bn + wave * 32 + cf * 16 + l15;
      #pragma unroll
      for (int r = 0; r < 4; r++) {
        int crow = bm + i * 16 + l4 * 4 + r;
        if (crow < N_NODES) C[(size_t)crow * D1 + ccol] = (_Float16)acc[i][cf][r];
      }
    }
    float ps[4], pd[4];
    #pragma unroll
    for (int r = 0; r < 4; r++) {
      ps[r] = acc[i][0][r] * sA0 + acc[i][1][r] * sA1;
      pd[r] = acc[i][0][r] * dA0 + acc[i][1][r] * dA1;
    }
    #pragma unroll
    for (int m = 1; m < 16; m <<= 1) {
      #pragma unroll
      for (int r = 0; r < 4; r++) {
        ps[r] += __shfl_xor(ps[r], m);
        pd[r] += __shfl_xor(pd[r], m);
      }
    }
    if (l15 == 0) {
      #pragma unroll
      for (int r = 0; r < 4; r++) {
        int crow = bm + i * 16 + l4 * 4 + r;
        if (crow < N_NODES) {
          as_[crow * HEADS + head] = ps[r];
          ad_[crow * HEADS + head] = pd[r];
        }
      }
    }
  }
}

// ---------------- CSR scan: per-node sub-counter prefix + block scan ----------------
__global__ __launch_bounds__(256) void scan_partial(const int* __restrict__ deg4,
                                                    int4* __restrict__ pre4,
                                                    int* __restrict__ deg,
                                                    int* __restrict__ offs,
                                                    int* __restrict__ part) {
  __shared__ int ts[256];
  const int tid = threadIdx.x;
  const int n = blockIdx.x * 256 + tid;
  int4 v = {0, 0, 0, 0};
  if (n < N_NODES) v = *(const int4*)(deg4 + n * 4);
  int4 p;
  p.x = 0; p.y = v.x; p.z = v.x + v.y; p.w = v.x + v.y + v.z;
  const int tot = p.w + v.w + 1;    // +1 = self-loop
  if (n < N_NODES) { pre4[n] = p; deg[n] = tot; }
  ts[tid] = (n < N_NODES) ? tot : 0;
  __syncthreads();
  for (int st = 1; st < 256; st <<= 1) {
    int t = (tid >= st) ? ts[tid - st] : 0;
    __syncthreads();
    ts[tid] += t;
    __syncthreads();
  }
  if (tid == 255) part[blockIdx.x] = ts[255];
  if (n < N_NODES) offs[n] = ts[tid] - tot;
}

// apply block offsets; emit flattened offs4; write self-loop src (atomic-free)
__global__ __launch_bounds__(256) void scan_apply(int* __restrict__ offs,
                                                  const int* __restrict__ part,
                                                  const int* __restrict__ deg,
                                                  const int4* __restrict__ pre4,
                                                  int4* __restrict__ offs4,
                                                  int* __restrict__ srcs) {
  __shared__ int sp[SCAN_NB];
  const int tid = threadIdx.x;
  if (tid < SCAN_NB) sp[tid] = part[tid];
  __syncthreads();
  if (tid == 0) {
    int run = 0;
    #pragma unroll 1
    for (int b = 0; b < SCAN_NB; b++) { int v = sp[b]; sp[b] = run; run += v; }
  }
  __syncthreads();
  int n = blockIdx.x * 256 + tid;
  if (n < N_NODES) {
    int o = offs[n] + sp[n >> 8];
    offs[n] = o;
    int4 p = pre4[n];
    int4 o4;
    o4.x = o + p.x; o4.y = o + p.y; o4.z = o + p.z; o4.w = o + p.w;
    offs4[n] = o4;
    srcs[o + deg[n] - 1] = n;     // self-loop occupies the final slot
  }
}

// ---------------- scatter: atomic-free via rank + flattened offs4 ----------------
__global__ void scatter_edges(const int* __restrict__ esrc, const int* __restrict__ edst,
                              const int* __restrict__ offs4, const int* __restrict__ rank,
                              int* __restrict__ srcs) {
  int e = blockIdx.x * blockDim.x + threadIdx.x;
  if (e >= N_EDGES) return;
  int s = esrc[e], d = edst[e];
  srcs[offs4[(d << 2) + (e & 3)] + rank[e]] = s;
}

// ---- layer-1 aggregation + bias + ELU + FUSED gemm2+attn2 (h2 never materialized) ----
// one wave per node; epilogue: per-lane 4x16 partials vs W2^T(LDS), 64-lane butterfly,
// lane 0 stores g2(fp16) + as2/ad2.
__global__ __launch_bounds__(256) void node_aggr1_g2(
    const int* __restrict__ offs, const int* __restrict__ deg,
    const int* __restrict__ srcs,
    const float* __restrict__ as_, const float* __restrict__ ad_,
    const _Float16* __restrict__ h, const float* __restrict__ bias,
    const float* __restrict__ W2, const float* __restrict__ att_s2,
    const float* __restrict__ att_d2,
    _Float16* __restrict__ g2, float* __restrict__ as2, float* __restrict__ ad2) {
  __shared__ float Bst[OUT_DIM * D1];   // W2^T: [c][k], 16KB
  __shared__ float s2v[OUT_DIM], d2v[OUT_DIM];
  const int tid = threadIdx.x;
  #pragma unroll
  for (int i = 0; i < OUT_DIM * D1 / 256; i++) {
    int idx = tid + i * 256;
    Bst[(idx & 15) * D1 + (idx >> 4)] = W2[idx];
  }
  if (tid < OUT_DIM) { s2v[tid] = att_s2[tid]; d2v[tid] = att_d2[tid]; }
  __syncthreads();

  const int n = blockIdx.x * 4 + (tid >> 6);
  const int lane = tid & 63;
  const int base = offs[n], dg = deg[n];
  const int hd = lane >> 3;
  const float adn = ad_[n * HEADS + hd];
  const unsigned c0 = lane * 4;
  float4 acc = {0.f, 0.f, 0.f, 0.f};
  float se = 0.f;
  int e = 0;
  for (; e + 8 <= dg; e += 8) {
    int s[8];
    #pragma unroll
    for (int u = 0; u < 8; u++) s[u] = __builtin_amdgcn_readfirstlane(srcs[base + e + u]);
    half4 hv[8];
    #pragma unroll
    for (int u = 0; u < 8; u++) hv[u] = *(const half4*)(h + ((unsigned)s[u] * D1 + c0));
    float ex[8];
    #pragma unroll
    for (int u = 0; u < 8; u++) ex[u] = __expf(lrelu(as_[(unsigned)s[u] * HEADS + hd] + adn));
    #pragma unroll
    for (int u = 0; u < 8; u++) {
      se += ex[u];
      acc.x += ex[u] * (float)hv[u].x; acc.y += ex[u] * (float)hv[u].y;
      acc.z += ex[u] * (float)hv[u].z; acc.w += ex[u] * (float)hv[u].w;
    }
  }
  for (; e + 4 <= dg; e += 4) {
    int s[4];
    #pragma unroll
    for (int u = 0; u < 4; u++) s[u] = __builtin_amdgcn_readfirstlane(srcs[base + e + u]);
    half4 hv[4];
    #pragma unroll
    for (int u = 0; u < 4; u++) hv[u] = *(const half4*)(h + ((unsigned)s[u] * D1 + c0));
    float ex[4];
    #pragma unroll
    for (int u = 0; u < 4; u++) ex[u] = __expf(lrelu(as_[(unsigned)s[u] * HEADS + hd] + adn));
    #pragma unroll
    for (int u = 0; u < 4; u++) {
      se += ex[u];
      acc.x += ex[u] * (float)hv[u].x; acc.y += ex[u] * (float)hv[u].y;
      acc.z += ex[u] * (float)hv[u].z; acc.w += ex[u] * (float)hv[u].w;
    }
  }
  for (; e < dg; e++) {
    int s = __builtin_amdgcn_readfirstlane(srcs[base + e]);
    float ex = __expf(lrelu(as_[(unsigned)s * HEADS + hd] + adn));
    half4 hv = *(const half4*)(h + ((unsigned)s * D1 + c0));
    se += ex;
    acc.x += ex * (float)hv.x; acc.y += ex * (float)hv.y;
    acc.z += ex * (float)hv.z; acc.w += ex * (float)hv.w;
  }
  const float inv = 1.f / (se + 1e-16f);
  float4 bv = *(const float4*)(bias + c0);
  float4 v;
  v.x = acc.x * inv + bv.x; v.y = acc.y * inv + bv.y;
  v.z = acc.z * inv + bv.z; v.w = acc.w * inv + bv.w;
  v.x = (v.x > 0.f) ? v.x : expm1f(v.x);
  v.y = (v.y > 0.f) ? v.y : expm1f(v.y);
  v.z = (v.z > 0.f) ? v.z : expm1f(v.z);
  v.w = (v.w > 0.f) ? v.w : expm1f(v.w);

  // fused gemm2: p[c] = <h2 row, W2[:,c]>  via per-lane partials + butterfly
  float p[OUT_DIM];
  #pragma unroll
  for (int c = 0; c < OUT_DIM; c++) {
    float4 wv = *(const float4*)&Bst[c * D1 + c0];
    p[c] = v.x * wv.x + v.y * wv.y + v.z * wv.z + v.w * wv.w;
  }
  #pragma unroll
  for (int m = 1; m < 64; m <<= 1) {
    #pragma unroll
    for (int c = 0; c < OUT_DIM; c++) p[c] += __shfl_xor(p[c], m);
  }
  if (lane == 0) {
    _Float16 gh[OUT_DIM];
    float ps = 0.f, pd = 0.f;
    #pragma unroll
    for (int c = 0; c < OUT_DIM; c++) {
      gh[c] = (_Float16)p[c];
      ps += p[c] * s2v[c];
      pd += p[c] * d2v[c];
    }
    *(half8*)(g2 + n * OUT_DIM) = *(half8*)gh;
    *(half8*)(g2 + n * OUT_DIM + 8) = *(half8*)(gh + 8);
    as2[n] = ps;
    ad2[n] = pd;
  }
}

// ---------------- layer-2 single-pass aggregation + bias (fp16 g2) ----------------
__global__ __launch_bounds__(256) void node_aggr2(
    const int* __restrict__ offs, const int* __restrict__ deg,
    const int* __restrict__ srcs,
    const float* __restrict__ as_, const float* __restrict__ ad_,
    const _Float16* __restrict__ g, const float* __restrict__ bias,
    float* __restrict__ out) {
  const int n = blockIdx.x * 4 + (threadIdx.x >> 6);
  const int lane = threadIdx.x & 63;
  const int base = offs[n], dg = deg[n];
  const float adn = ad_[n];
  const int c = lane & 15, grp = lane >> 4;
  float acc = 0.f, se = 0.f;
  int e = grp;
  for (; e + 8 <= dg + grp; e += 8) {
    unsigned s0 = srcs[base + e], s1 = srcs[base + e + 4];
    float e0 = __expf(lrelu(as_[s0] + adn));
    float e1 = __expf(lrelu(as_[s1] + adn));
    float g0 = (float)g[s0 * OUT_DIM + c], g1 = (float)g[s1 * OUT_DIM + c];
    se += e0 + e1;
    acc += e0 * g0 + e1 * g1;
  }
  for (; e < dg; e += 4) {
    unsigned s = srcs[base + e];
    float ex = __expf(lrelu(as_[s] + adn));
    se += ex;
    acc += ex * (float)g[s * OUT_DIM + c];
  }
  acc += __shfl_xor(acc, 16); se += __shfl_xor(se, 16);
  acc += __shfl_xor(acc, 32); se += __shfl_xor(se, 32);
  if (lane < OUT_DIM) out[n * OUT_DIM + c] = acc / (se + 1e-16f) + bias[c];
}

extern "C" void kernel_launch(void* const* d_in, const int* in_sizes, int n_in,
                              void* d_out, int out_size, void* d_ws, size_t ws_size,
                              hipStream_t stream) {
  const float* x      = (const float*)d_in[0];
  const int*   ei     = (const int*)d_in[1];
  const float* W1     = (const float*)d_in[2];
  const float* att_s1 = (const float*)d_in[3];
  const float* att_d1 = (const float*)d_in[4];
  const float* b1     = (const float*)d_in[5];
  const float* W2     = (const float*)d_in[6];
  const float* att_s2 = (const float*)d_in[7];
  const float* att_d2 = (const float*)d_in[8];
  const float* b2     = (const float*)d_in[9];
  float* out = (float*)d_out;
  const int* esrc = ei;
  const int* edst = ei + N_EDGES;

  char* w = (char*)d_ws;
  _Float16* h1f = (_Float16*)w; w += (size_t)N_NODES * D1 * 2;    // 25.6 MB fp16 h1
  unsigned short* W1t_hi = (unsigned short*)w;  w += (size_t)IN_DIM * D1 * 2;
  unsigned short* W1t_lo = (unsigned short*)w;  w += (size_t)IN_DIM * D1 * 2;
  float* as1 = (float*)w;       w += (size_t)N_NODES * HEADS * 4;
  float* ad1 = (float*)w;       w += (size_t)N_NODES * HEADS * 4;
  _Float16* g2 = (_Float16*)w;  w += (size_t)N_NODES * OUT_DIM * 2;
  float* as2 = (float*)w;       w += (size_t)N_NODES * 4;
  float* ad2 = (float*)w;       w += (size_t)N_NODES * 4;
  int* deg4  = (int*)w;         w += (size_t)N_NODES * 16;  // 4 sub-counters/node
  int4* pre4 = (int4*)w;        w += (size_t)N_NODES * 16;  // per-node sub-prefix
  int4* offs4 = (int4*)w;       w += (size_t)N_NODES * 16;  // flattened sub-offsets
  int* deg   = (int*)w;         w += (size_t)N_NODES * 4;
  int* offs  = (int*)w;         w += (size_t)N_NODES * 4;
  int* part  = (int*)w;         w += (size_t)256 * 4;
  int* rank  = (int*)w;         w += (size_t)N_EDGES * 4;         // 3.2 MB
  int* srcs  = (int*)w;         w += (size_t)E_TOT * 4;           // 3.4 MB

  hipMemsetAsync(deg4, 0, (size_t)N_NODES * 16, stream);

  prep_w<<<IN_DIM * D1 / 256, 256, 0, stream>>>(W1, W1t_hi, W1t_lo);

  gemm1_count<<<CNT8_NB + G1_NB, 256, 0, stream>>>(
      x, W1t_hi, W1t_lo, att_s1, att_d1, h1f, as1, ad1, edst, deg4, rank);

  scan_partial<<<SCAN_NB, 256, 0, stream>>>(deg4, pre4, deg, offs, part);
  scan_apply<<<SCAN_NB, 256, 0, stream>>>(offs, part, deg, pre4, offs4, srcs);
  scatter_edges<<<(N_EDGES + 255) / 256, 256, 0, stream>>>(esrc, edst, (const int*)offs4, rank, srcs);

  node_aggr1_g2<<<N_NODES / 4, 256, 0, stream>>>(
      offs, deg, srcs, as1, ad1, h1f, b1, W2, att_s2, att_d2, g2, as2, ad2);

  node_aggr2<<<N_NODES / 4, 256, 0, stream>>>(offs, deg, srcs, as2, ad2, g2, b2, out);
}

// Round 17
// 206.341 us; speedup vs baseline: 1.1897x; 1.1897x over previous
//
#include <hip/hip_runtime.h>

#define N_NODES 50000
#define N_EDGES 800000
#define E_TOT   (N_EDGES + N_NODES)
#define IN_DIM  256
#define HID     32
#define HEADS   8
#define D1      256      // HEADS*HID
#define OUT_DIM 16

#define SCAN_NB ((N_NODES + 255) / 256)                     // 196 (1 node per thread)
#define CNT8_NB ((N_EDGES + 2047) / 2048)                   // 391 count blocks (8 edges/thread)
#define G1_NB   ((D1 / 128) * ((N_NODES + 127) / 128))      // 2*391 = 782 gemm1 blocks

typedef __attribute__((ext_vector_type(8))) short bf16x8;
typedef __attribute__((ext_vector_type(4))) float f32x4;
typedef __attribute__((ext_vector_type(4))) _Float16 half4;
typedef __attribute__((ext_vector_type(8))) _Float16 half8;

// ---- f32 <-> bf16 split helpers ----
__device__ __forceinline__ unsigned short f2bf(float f) {
  unsigned u = __float_as_uint(f);
  return (unsigned short)((u + 0x7FFFu + ((u >> 16) & 1u)) >> 16);
}
__device__ __forceinline__ float bf2f(unsigned short b) {
  return __uint_as_float(((unsigned)b) << 16);
}
__device__ __forceinline__ float lrelu(float a) { return (a > 0.f) ? a : 0.2f * a; }

// ---------------- prep: transpose + split W1 only (tiny, 256KB) ----------------
__global__ void prep_w(const float* __restrict__ W, unsigned short* __restrict__ Wth,
                       unsigned short* __restrict__ Wtl) {
  int t = blockIdx.x * blockDim.x + threadIdx.x;
  if (t >= IN_DIM * D1) return;
  int n = t >> 8, k = t & 255;
  float v = W[k * D1 + n];
  unsigned short h = f2bf(v);
  Wth[n * IN_DIM + k] = h;
  Wtl[n * IN_DIM + k] = f2bf(v - bf2f(h));
}

// ---- GEMM1 (fp32 x, in-register split) + attn1 + edge-count fused ----
__global__ __launch_bounds__(256) void gemm1_count(
    const float* __restrict__ x,
    const unsigned short* __restrict__ Bth_g, const unsigned short* __restrict__ Btl_g,
    const float* __restrict__ att_s, const float* __restrict__ att_d,
    _Float16* __restrict__ C, float* __restrict__ as_, float* __restrict__ ad_,
    const int* __restrict__ edst, int* __restrict__ deg4, int* __restrict__ rank) {
  const int bid = blockIdx.x;
  if (bid < CNT8_NB) {
    const int eb = bid * 2048 + threadIdx.x;
    #pragma unroll
    for (int u = 0; u < 8; u++) {
      int e = eb + u * 256;
      if (e < N_EDGES) {
        int d = edst[e];
        rank[e] = atomicAdd(&deg4[(d << 2) + (e & 3)], 1);
      }
    }
    return;
  }
  __shared__ short Ah[128][40], Al[128][40];
  __shared__ short Bh[128][40], Bl[128][40];
  const int gb = bid - CNT8_NB;
  const int bm = (gb >> 1) * 128, bn = (gb & 1) * 128;
  const int tid = threadIdx.x;
  const int wave = tid >> 6, lane = tid & 63;
  const int l15 = lane & 15, l4 = lane >> 4;
  f32x4 acc[8][2] = {};
  const int sr2 = tid >> 1, sc2 = (tid & 1) * 16;
  const bf16x8 zv = {0, 0, 0, 0, 0, 0, 0, 0};
  for (int k0 = 0; k0 < IN_DIM; k0 += 32) {
    int grow = bm + sr2;
    if (grow < N_NODES) {
      const float4* xp = (const float4*)&x[(size_t)grow * IN_DIM + k0 + sc2];
      #pragma unroll
      for (int j = 0; j < 4; j++) {
        float4 v = xp[j];
        ushort4 hh, ll;
        hh.x = f2bf(v.x); ll.x = f2bf(v.x - bf2f(hh.x));
        hh.y = f2bf(v.y); ll.y = f2bf(v.y - bf2f(hh.y));
        hh.z = f2bf(v.z); ll.z = f2bf(v.z - bf2f(hh.z));
        hh.w = f2bf(v.w); ll.w = f2bf(v.w - bf2f(hh.w));
        *(ushort4*)&Ah[sr2][sc2 + j * 4] = hh;
        *(ushort4*)&Al[sr2][sc2 + j * 4] = ll;
      }
    } else {
      *(bf16x8*)&Ah[sr2][sc2] = zv;
      *(bf16x8*)&Ah[sr2][sc2 + 8] = zv;
      *(bf16x8*)&Al[sr2][sc2] = zv;
      *(bf16x8*)&Al[sr2][sc2 + 8] = zv;
    }
    {
      const bf16x8* sH = (const bf16x8*)&Bth_g[(size_t)(bn + sr2) * IN_DIM + k0 + sc2];
      const bf16x8* sL = (const bf16x8*)&Btl_g[(size_t)(bn + sr2) * IN_DIM + k0 + sc2];
      *(bf16x8*)&Bh[sr2][sc2] = sH[0];
      *(bf16x8*)&Bh[sr2][sc2 + 8] = sH[1];
      *(bf16x8*)&Bl[sr2][sc2] = sL[0];
      *(bf16x8*)&Bl[sr2][sc2 + 8] = sL[1];
    }
    __syncthreads();
    bf16x8 bh0 = *(bf16x8*)&Bh[wave * 32 + l15][l4 * 8];
    bf16x8 bl0 = *(bf16x8*)&Bl[wave * 32 + l15][l4 * 8];
    bf16x8 bh1 = *(bf16x8*)&Bh[wave * 32 + 16 + l15][l4 * 8];
    bf16x8 bl1 = *(bf16x8*)&Bl[wave * 32 + 16 + l15][l4 * 8];
    #pragma unroll
    for (int i = 0; i < 8; i++) {
      bf16x8 ah = *(bf16x8*)&Ah[i * 16 + l15][l4 * 8];
      bf16x8 al = *(bf16x8*)&Al[i * 16 + l15][l4 * 8];
      acc[i][0] = __builtin_amdgcn_mfma_f32_16x16x32_bf16(ah, bh0, acc[i][0], 0, 0, 0);
      acc[i][0] = __builtin_amdgcn_mfma_f32_16x16x32_bf16(ah, bl0, acc[i][0], 0, 0, 0);
      acc[i][0] = __builtin_amdgcn_mfma_f32_16x16x32_bf16(al, bh0, acc[i][0], 0, 0, 0);
      acc[i][1] = __builtin_amdgcn_mfma_f32_16x16x32_bf16(ah, bh1, acc[i][1], 0, 0, 0);
      acc[i][1] = __builtin_amdgcn_mfma_f32_16x16x32_bf16(ah, bl1, acc[i][1], 0, 0, 0);
      acc[i][1] = __builtin_amdgcn_mfma_f32_16x16x32_bf16(al, bh1, acc[i][1], 0, 0, 0);
    }
    __syncthreads();
  }
  const int head = (bn >> 5) + wave;
  const float sA0 = att_s[head * HID + l15];
  const float sA1 = att_s[head * HID + 16 + l15];
  const float dA0 = att_d[head * HID + l15];
  const float dA1 = att_d[head * HID + 16 + l15];
  #pragma unroll
  for (int i = 0; i < 8; i++) {
    #pragma unroll
    for (int cf = 0; cf < 2; cf++) {
      const int ccol = bn + wave * 32 + cf * 16 + l15;
      #pragma unroll
      for (int r = 0; r < 4; r++) {
        int crow = bm + i * 16 + l4 * 4 + r;
        if (crow < N_NODES) C[(size_t)crow * D1 + ccol] = (_Float16)acc[i][cf][r];
      }
    }
    float ps[4], pd[4];
    #pragma unroll
    for (int r = 0; r < 4; r++) {
      ps[r] = acc[i][0][r] * sA0 + acc[i][1][r] * sA1;
      pd[r] = acc[i][0][r] * dA0 + acc[i][1][r] * dA1;
    }
    #pragma unroll
    for (int m = 1; m < 16; m <<= 1) {
      #pragma unroll
      for (int r = 0; r < 4; r++) {
        ps[r] += __shfl_xor(ps[r], m);
        pd[r] += __shfl_xor(pd[r], m);
      }
    }
    if (l15 == 0) {
      #pragma unroll
      for (int r = 0; r < 4; r++) {
        int crow = bm + i * 16 + l4 * 4 + r;
        if (crow < N_NODES) {
          as_[crow * HEADS + head] = ps[r];
          ad_[crow * HEADS + head] = pd[r];
        }
      }
    }
  }
}

// ---------------- CSR scan: per-node sub-counter prefix + block scan ----------------
__global__ __launch_bounds__(256) void scan_partial(const int* __restrict__ deg4,
                                                    int4* __restrict__ pre4,
                                                    int* __restrict__ deg,
                                                    int* __restrict__ offs,
                                                    int* __restrict__ part) {
  __shared__ int ts[256];
  const int tid = threadIdx.x;
  const int n = blockIdx.x * 256 + tid;
  int4 v = {0, 0, 0, 0};
  if (n < N_NODES) v = *(const int4*)(deg4 + n * 4);
  int4 p;
  p.x = 0; p.y = v.x; p.z = v.x + v.y; p.w = v.x + v.y + v.z;
  const int tot = p.w + v.w + 1;    // +1 = self-loop
  if (n < N_NODES) { pre4[n] = p; deg[n] = tot; }
  ts[tid] = (n < N_NODES) ? tot : 0;
  __syncthreads();
  for (int st = 1; st < 256; st <<= 1) {
    int t = (tid >= st) ? ts[tid - st] : 0;
    __syncthreads();
    ts[tid] += t;
    __syncthreads();
  }
  if (tid == 255) part[blockIdx.x] = ts[255];
  if (n < N_NODES) offs[n] = ts[tid] - tot;
}

// apply block offsets; emit flattened offs4; write self-loop src (atomic-free)
__global__ __launch_bounds__(256) void scan_apply(int* __restrict__ offs,
                                                  const int* __restrict__ part,
                                                  const int* __restrict__ deg,
                                                  const int4* __restrict__ pre4,
                                                  int4* __restrict__ offs4,
                                                  int* __restrict__ srcs) {
  __shared__ int sp[SCAN_NB];
  const int tid = threadIdx.x;
  if (tid < SCAN_NB) sp[tid] = part[tid];
  __syncthreads();
  if (tid == 0) {
    int run = 0;
    #pragma unroll 1
    for (int b = 0; b < SCAN_NB; b++) { int v = sp[b]; sp[b] = run; run += v; }
  }
  __syncthreads();
  int n = blockIdx.x * 256 + tid;
  if (n < N_NODES) {
    int o = offs[n] + sp[n >> 8];
    offs[n] = o;
    int4 p = pre4[n];
    int4 o4;
    o4.x = o + p.x; o4.y = o + p.y; o4.z = o + p.z; o4.w = o + p.w;
    offs4[n] = o4;
    srcs[o + deg[n] - 1] = n;     // self-loop occupies the final slot
  }
}

// ---------------- scatter: atomic-free via rank + flattened offs4 ----------------
__global__ void scatter_edges(const int* __restrict__ esrc, const int* __restrict__ edst,
                              const int* __restrict__ offs4, const int* __restrict__ rank,
                              int* __restrict__ srcs) {
  int e = blockIdx.x * blockDim.x + threadIdx.x;
  if (e >= N_EDGES) return;
  int s = esrc[e], d = edst[e];
  srcs[offs4[(d << 2) + (e & 3)] + rank[e]] = s;
}

// ---------------- layer-1 single-pass aggregation + bias + ELU (out fp16) ----------------
__global__ __launch_bounds__(256) void node_aggr1(
    const int* __restrict__ offs, const int* __restrict__ deg,
    const int* __restrict__ srcs,
    const float* __restrict__ as_, const float* __restrict__ ad_,
    const _Float16* __restrict__ h, const float* __restrict__ bias,
    _Float16* __restrict__ out) {
  const int n = blockIdx.x * 4 + (threadIdx.x >> 6);
  const int lane = threadIdx.x & 63;
  const int base = offs[n], dg = deg[n];
  const int hd = lane >> 3;
  const float adn = ad_[n * HEADS + hd];
  const unsigned c0 = lane * 4;
  float4 acc = {0.f, 0.f, 0.f, 0.f};
  float se = 0.f;
  int e = 0;
  for (; e + 8 <= dg; e += 8) {
    int s[8];
    #pragma unroll
    for (int u = 0; u < 8; u++) s[u] = __builtin_amdgcn_readfirstlane(srcs[base + e + u]);
    half4 hv[8];
    #pragma unroll
    for (int u = 0; u < 8; u++) hv[u] = *(const half4*)(h + ((unsigned)s[u] * D1 + c0));
    float ex[8];
    #pragma unroll
    for (int u = 0; u < 8; u++) ex[u] = __expf(lrelu(as_[(unsigned)s[u] * HEADS + hd] + adn));
    #pragma unroll
    for (int u = 0; u < 8; u++) {
      se += ex[u];
      acc.x += ex[u] * (float)hv[u].x; acc.y += ex[u] * (float)hv[u].y;
      acc.z += ex[u] * (float)hv[u].z; acc.w += ex[u] * (float)hv[u].w;
    }
  }
  for (; e + 4 <= dg; e += 4) {
    int s[4];
    #pragma unroll
    for (int u = 0; u < 4; u++) s[u] = __builtin_amdgcn_readfirstlane(srcs[base + e + u]);
    half4 hv[4];
    #pragma unroll
    for (int u = 0; u < 4; u++) hv[u] = *(const half4*)(h + ((unsigned)s[u] * D1 + c0));
    float ex[4];
    #pragma unroll
    for (int u = 0; u < 4; u++) ex[u] = __expf(lrelu(as_[(unsigned)s[u] * HEADS + hd] + adn));
    #pragma unroll
    for (int u = 0; u < 4; u++) {
      se += ex[u];
      acc.x += ex[u] * (float)hv[u].x; acc.y += ex[u] * (float)hv[u].y;
      acc.z += ex[u] * (float)hv[u].z; acc.w += ex[u] * (float)hv[u].w;
    }
  }
  for (; e < dg; e++) {
    int s = __builtin_amdgcn_readfirstlane(srcs[base + e]);
    float ex = __expf(lrelu(as_[(unsigned)s * HEADS + hd] + adn));
    half4 hv = *(const half4*)(h + ((unsigned)s * D1 + c0));
    se += ex;
    acc.x += ex * (float)hv.x; acc.y += ex * (float)hv.y;
    acc.z += ex * (float)hv.z; acc.w += ex * (float)hv.w;
  }
  const float inv = 1.f / (se + 1e-16f);
  float4 bv = *(const float4*)(bias + c0);
  float4 v;
  v.x = acc.x * inv + bv.x; v.y = acc.y * inv + bv.y;
  v.z = acc.z * inv + bv.z; v.w = acc.w * inv + bv.w;
  v.x = (v.x > 0.f) ? v.x : expm1f(v.x);
  v.y = (v.y > 0.f) ? v.y : expm1f(v.y);
  v.z = (v.z > 0.f) ? v.z : expm1f(v.z);
  v.w = (v.w > 0.f) ? v.w : expm1f(v.w);
  half4 ov;
  ov.x = (_Float16)v.x; ov.y = (_Float16)v.y; ov.z = (_Float16)v.z; ov.w = (_Float16)v.w;
  *(half4*)(out + ((unsigned)n * D1 + c0)) = ov;
}

// ---------------- GEMM2 + attn2 fused: g2(fp16) = h2 @ W2; W2 in LDS; half8 A loads ----------------
__global__ __launch_bounds__(256) void gemm2_attn2(
    const _Float16* __restrict__ A, const float* __restrict__ B,
    const float* __restrict__ att_s, const float* __restrict__ att_d,
    _Float16* __restrict__ C, float* __restrict__ as_, float* __restrict__ ad_) {
  __shared__ float Bs[D1 * OUT_DIM];   // 16 KB
  const int tid = threadIdx.x;
  #pragma unroll
  for (int i = 0; i < D1 * OUT_DIM / 4 / 256; i++)
    ((float4*)Bs)[tid + i * 256] = ((const float4*)B)[tid + i * 256];
  __syncthreads();
  const int t = blockIdx.x * 256 + tid;
  const int n = t >> 4, c = t & 15;
  const _Float16* arow = A + (size_t)n * D1;
  float acc = 0.f;
  #pragma unroll
  for (int k0 = 0; k0 < D1; k0 += 8) {
    half8 av = *(const half8*)&arow[k0];
    #pragma unroll
    for (int j = 0; j < 8; j++) acc += (float)av[j] * Bs[(k0 + j) * OUT_DIM + c];
  }
  C[t] = (_Float16)acc;
  float ps = acc * att_s[c], pd = acc * att_d[c];
  #pragma unroll
  for (int mS = 1; mS < 16; mS <<= 1) {
    ps += __shfl_xor(ps, mS);
    pd += __shfl_xor(pd, mS);
  }
  if (c == 0) { as_[n] = ps; ad_[n] = pd; }
}

// ---------------- layer-2 single-pass aggregation + bias (fp16 g2) ----------------
__global__ __launch_bounds__(256) void node_aggr2(
    const int* __restrict__ offs, const int* __restrict__ deg,
    const int* __restrict__ srcs,
    const float* __restrict__ as_, const float* __restrict__ ad_,
    const _Float16* __restrict__ g, const float* __restrict__ bias,
    float* __restrict__ out) {
  const int n = blockIdx.x * 4 + (threadIdx.x >> 6);
  const int lane = threadIdx.x & 63;
  const int base = offs[n], dg = deg[n];
  const float adn = ad_[n];
  const int c = lane & 15, grp = lane >> 4;
  float acc = 0.f, se = 0.f;
  int e = grp;
  for (; e + 8 <= dg + grp; e += 8) {
    unsigned s0 = srcs[base + e], s1 = srcs[base + e + 4];
    float e0 = __expf(lrelu(as_[s0] + adn));
    float e1 = __expf(lrelu(as_[s1] + adn));
    float g0 = (float)g[s0 * OUT_DIM + c], g1 = (float)g[s1 * OUT_DIM + c];
    se += e0 + e1;
    acc += e0 * g0 + e1 * g1;
  }
  for (; e < dg; e += 4) {
    unsigned s = srcs[base + e];
    float ex = __expf(lrelu(as_[s] + adn));
    se += ex;
    acc += ex * (float)g[s * OUT_DIM + c];
  }
  acc += __shfl_xor(acc, 16); se += __shfl_xor(se, 16);
  acc += __shfl_xor(acc, 32); se += __shfl_xor(se, 32);
  if (lane < OUT_DIM) out[n * OUT_DIM + c] = acc / (se + 1e-16f) + bias[c];
}

extern "C" void kernel_launch(void* const* d_in, const int* in_sizes, int n_in,
                              void* d_out, int out_size, void* d_ws, size_t ws_size,
                              hipStream_t stream) {
  const float* x      = (const float*)d_in[0];
  const int*   ei     = (const int*)d_in[1];
  const float* W1     = (const float*)d_in[2];
  const float* att_s1 = (const float*)d_in[3];
  const float* att_d1 = (const float*)d_in[4];
  const float* b1     = (const float*)d_in[5];
  const float* W2     = (const float*)d_in[6];
  const float* att_s2 = (const float*)d_in[7];
  const float* att_d2 = (const float*)d_in[8];
  const float* b2     = (const float*)d_in[9];
  float* out = (float*)d_out;
  const int* esrc = ei;
  const int* edst = ei + N_EDGES;

  char* w = (char*)d_ws;
  _Float16* h1f = (_Float16*)w; w += (size_t)N_NODES * D1 * 2;    // 25.6 MB fp16 h1
  _Float16* h2  = (_Float16*)w; w += (size_t)N_NODES * D1 * 2;    // 25.6 MB fp16 h2
  unsigned short* W1t_hi = (unsigned short*)w;  w += (size_t)IN_DIM * D1 * 2;
  unsigned short* W1t_lo = (unsigned short*)w;  w += (size_t)IN_DIM * D1 * 2;
  float* as1 = (float*)w;       w += (size_t)N_NODES * HEADS * 4;
  float* ad1 = (float*)w;       w += (size_t)N_NODES * HEADS * 4;
  _Float16* g2 = (_Float16*)w;  w += (size_t)N_NODES * OUT_DIM * 2;
  float* as2 = (float*)w;       w += (size_t)N_NODES * 4;
  float* ad2 = (float*)w;       w += (size_t)N_NODES * 4;
  int* deg4  = (int*)w;         w += (size_t)N_NODES * 16;  // 4 sub-counters/node
  int4* pre4 = (int4*)w;        w += (size_t)N_NODES * 16;  // per-node sub-prefix
  int4* offs4 = (int4*)w;       w += (size_t)N_NODES * 16;  // flattened sub-offsets
  int* deg   = (int*)w;         w += (size_t)N_NODES * 4;
  int* offs  = (int*)w;         w += (size_t)N_NODES * 4;
  int* part  = (int*)w;         w += (size_t)256 * 4;
  int* rank  = (int*)w;         w += (size_t)N_EDGES * 4;         // 3.2 MB
  int* srcs  = (int*)w;         w += (size_t)E_TOT * 4;           // 3.4 MB

  hipMemsetAsync(deg4, 0, (size_t)N_NODES * 16, stream);

  prep_w<<<IN_DIM * D1 / 256, 256, 0, stream>>>(W1, W1t_hi, W1t_lo);

  gemm1_count<<<CNT8_NB + G1_NB, 256, 0, stream>>>(
      x, W1t_hi, W1t_lo, att_s1, att_d1, h1f, as1, ad1, edst, deg4, rank);

  scan_partial<<<SCAN_NB, 256, 0, stream>>>(deg4, pre4, deg, offs, part);
  scan_apply<<<SCAN_NB, 256, 0, stream>>>(offs, part, deg, pre4, offs4, srcs);
  scatter_edges<<<(N_EDGES + 255) / 256, 256, 0, stream>>>(esrc, edst, (const int*)offs4, rank, srcs);

  node_aggr1<<<N_NODES / 4, 256, 0, stream>>>(offs, deg, srcs, as1, ad1, h1f, b1, h2);

  gemm2_attn2<<<N_NODES * OUT_DIM / 256, 256, 0, stream>>>(
      h2, W2, att_s2, att_d2, g2, as2, ad2);

  node_aggr2<<<N_NODES / 4, 256, 0, stream>>>(offs, deg, srcs, as2, ad2, g2, b2, out);
}